// Round 13
// baseline (35.483 us; speedup 1.0000x reference)
//
#include <hip/hip_runtime.h>

#define S    33
#define S2   1089
#define S3   35937
#define LUTN (3 * S3)           // 107811 (odd!)
#define NPIX (2048 * 2048)      // 4194304 pixels per channel
#define TABN S3                 // packed u32 LUT entries
#define TABB (TABN * 4)         // 143748 bytes of LDS
#define BLOCK 1024
#define PXBLK 16384             // pixels per block
#define GRID  (NPIX / PXBLK)    // 256 blocks = 1 per CU (LDS forces 1/CU)

// sched_barrier mask (LLVM SchedGroupMask): types ALLOWED to cross.
// allow SALU(0x4)+VMEM(0x10)+VMEM_READ(0x20)+VMEM_WRITE(0x40)+DS_WRITE(0x200)
// forbid ALU(0x1)+VALU(0x2)+DS_READ(0x100): gathers pinned above, consumers
// pinned below -> all 32 pair-reads outstanding before first consumer wait.
#define GATHER_FENCE() __builtin_amdgcn_sched_barrier(0x274)

// R9 body, phase C restructured: per 8-px tile, [addr+frac VALU] ->
// [32 LDS pair-reads clustered] -> GATHER_FENCE -> [extract+FMA+store].
__global__ __launch_bounds__(BLOCK, 4) void trilerp_fused(
        const float* __restrict__ img,
        const float* __restrict__ lut,
        float* __restrict__ out) {
    extern __shared__ unsigned tab[];
    const int tid = threadIdx.x;
    const int base_px = blockIdx.x * PXBLK;
    float* __restrict__ res = out + LUTN;   // output 1 (region only 4B-aligned)

    // ---- Phase A: lut passthrough (output 0), float4-coalesced ----
    {
        int g = blockIdx.x * BLOCK + tid;
        if (g < LUTN / 4) {                  // 26952 float4s
            *(float4*)(out + g * 4) = *(const float4*)(lut + g * 4);
        } else if (g == LUTN / 4) {          // 3-float tail (LUTN odd)
            out[LUTN - 3] = lut[LUTN - 3];
            out[LUTN - 2] = lut[LUTN - 2];
            out[LUTN - 1] = lut[LUTN - 1];
        }
    }

    // ---- Phase B: pack lut -> LDS (8:8:8, byte3=0), lane-coalesced ----
    for (int k = tid; k < TABN; k += BLOCK) {
        float r = lut[k], g = lut[S3 + k], b = lut[2 * S3 + k];
        unsigned qr = (unsigned)fmaf(r, 255.f, 0.5f);
        unsigned qg = (unsigned)fmaf(g, 255.f, 0.5f);
        unsigned qb = (unsigned)fmaf(b, 255.f, 0.5f);
        tab[k] = qr | (qg << 8) | (qb << 16);
    }
    __syncthreads();

    // ---- Phase C: 2 tiles x 8 px, gather-clustered ----
    const float inv = 1.0f / 255.0f;
#pragma unroll
    for (int t = 0; t < 2; ++t) {
        int pa = base_px + (tid + (2 * t) * BLOCK) * 4;
        int pb = base_px + (tid + (2 * t + 1) * BLOCK) * 4;
        float4 xa = *(const float4*)(img + pa);
        float4 xb = *(const float4*)(img + pb);
        float4 ya = *(const float4*)(img + NPIX + pa);
        float4 yb = *(const float4*)(img + NPIX + pb);
        float4 za = *(const float4*)(img + 2 * NPIX + pa);
        float4 zb = *(const float4*)(img + 2 * NPIX + pb);
        float ax[8] = {xa.x, xa.y, xa.z, xa.w, xb.x, xb.y, xb.z, xb.w};
        float ay[8] = {ya.x, ya.y, ya.z, ya.w, yb.x, yb.y, yb.z, yb.w};
        float az[8] = {za.x, za.y, za.z, za.w, zb.x, zb.y, zb.z, zb.w};

        // -- stage 1: addresses + fractions for all 8 px --
        float fx[8], fy[8], fz[8];
        int bse[8];
#pragma unroll
        for (int i = 0; i < 8; ++i) {
            float px = ax[i] * 32.0f;          // img in [0,1) -> px in [0,32)
            float py = ay[i] * 32.0f;
            float pz = az[i] * 32.0f;
            int ix = (int)px & 31;             // &31: free OOB guard
            int iy = (int)py & 31;
            int iz = (int)pz & 31;
            fx[i] = __builtin_amdgcn_fractf(px);
            fy[i] = __builtin_amdgcn_fractf(py);
            fz[i] = __builtin_amdgcn_fractf(pz);
            bse[i] = (iz * S + iy) * S + ix;
        }

        // -- stage 2: ALL 32 pair-reads (64 dwords), clustered --
        unsigned c[8][8];
#pragma unroll
        for (int i = 0; i < 8; ++i) {
            int b0 = bse[i];
            c[i][0] = tab[b0];           c[i][1] = tab[b0 + 1];
            c[i][2] = tab[b0 + S];       c[i][3] = tab[b0 + S + 1];
            c[i][4] = tab[b0 + S2];      c[i][5] = tab[b0 + S2 + 1];
            c[i][6] = tab[b0 + S2 + S];  c[i][7] = tab[b0 + S2 + S + 1];
        }
        GATHER_FENCE();

        // -- stage 3: weights + extraction + FMA --
        float rr[8], gg[8], bb[8];
#pragma unroll
        for (int i = 0; i < 8; ++i) {
            float gx = 1.f - fx[i], gy = 1.f - fy[i], gz = 1.f - fz[i];
            float a00 = gy * gz, a10 = fy[i] * gz, a01 = gy * fz[i], a11 = fy[i] * fz[i];
            float w0 = gx * a00, w1 = fx[i] * a00, w2 = gx * a10, w3 = fx[i] * a10;
            float w4 = gx * a01, w5 = fx[i] * a01, w6 = gx * a11, w7 = fx[i] * a11;

            float R = 0.f, G = 0.f, B = 0.f;
            // byte extracts -> v_cvt_f32_ubyte{0,1,2}
#define ACC(cc, w)                                                        \
            R = fmaf((float)((cc) & 0xffu), (w), R);                      \
            G = fmaf((float)(((cc) >> 8) & 0xffu), (w), G);               \
            B = fmaf((float)(((cc) >> 16) & 0xffu), (w), B);
            ACC(c[i][0], w0) ACC(c[i][1], w1) ACC(c[i][2], w2) ACC(c[i][3], w3)
            ACC(c[i][4], w4) ACC(c[i][5], w5) ACC(c[i][6], w6) ACC(c[i][7], w7)
#undef ACC
            rr[i] = R * inv; gg[i] = G * inv; bb[i] = B * inv;
        }

        // -- stage 4: stores (VMEM_WRITE may sink across next tile's fence) --
#pragma unroll
        for (int g4 = 0; g4 < 2; ++g4) {
            int p = g4 ? pb : pa;
            const float* vr = rr + g4 * 4;
            const float* vg = gg + g4 * 4;
            const float* vb = bb + g4 * 4;
#pragma unroll
            for (int ch = 0; ch < 3; ++ch) {
                float* o = res + (size_t)ch * NPIX + p;
                const float* v = ch == 0 ? vr : (ch == 1 ? vg : vb);
                o[0] = v[0];
                *(float2*)(o + 1) = make_float2(v[1], v[2]);
                o[3] = v[3];
            }
        }
    }
}

extern "C" void kernel_launch(void* const* d_in, const int* in_sizes, int n_in,
                              void* d_out, int out_size, void* d_ws, size_t ws_size,
                              hipStream_t stream) {
    const float* lut = (const float*)d_in[0];
    const float* img = (const float*)d_in[1];
    float* out = (float*)d_out;

    // Allow >64KB dynamic LDS (idempotent attribute set, capture-safe).
    (void)hipFuncSetAttribute((const void*)trilerp_fused,
                              hipFuncAttributeMaxDynamicSharedMemorySize, TABB);

    trilerp_fused<<<GRID, BLOCK, TABB, stream>>>(img, lut, out);
}

// Round 14
// 26.491 us; speedup vs baseline: 1.3394x; 1.3394x over previous
//
#include <hip/hip_runtime.h>

#define S    33
#define S2   1089
#define S3   35937
#define LUTN (3 * S3)           // 107811 (odd!)
#define NPIX (2048 * 2048)      // 4194304 pixels per channel
#define TABN S3                 // packed u32 LUT entries
#define TABB (TABN * 4)         // 143748 bytes of LDS
#define BLOCK 1024
#define PXBLK 16384             // pixels per block
#define GRID  (NPIX / PXBLK)    // 256 blocks = 1 per CU (LDS forces 1/CU)

// FINAL (R9 structure, session best: 26.5us from 63.4 baseline).
// Design: whole 33^3 LUT packed 8:8:8 per-u32 lives in LDS (143.7KB);
// 8 corner reads/px are ds_read2_b32 pairs (no L1/L2 line amplification);
// byte extraction pattern-matches v_cvt_f32_ubyte{0,1,2}; weights-form
// trilerp (8 FMA/channel). Fused single kernel: passthrough + pack + compute.
// Established empirically (R2-R13): compiler holds <=~64 VGPR here — ILP
// forcing either re-serializes, nulls (waves_per_eu), or spills
// (sched_barrier mask -> +30MB scratch). 4 waves/SIMD is the TLP cap
// (143.7KB LDS; 70KB table did not give 2 blocks/CU). Practical plateau.
__global__ __launch_bounds__(BLOCK, 4) void trilerp_fused(
        const float* __restrict__ img,
        const float* __restrict__ lut,
        float* __restrict__ out) {
    extern __shared__ unsigned tab[];
    const int tid = threadIdx.x;
    const int base_px = blockIdx.x * PXBLK;
    float* __restrict__ res = out + LUTN;   // output 1 (region only 4B-aligned)

    // ---- Phase A: lut passthrough (output 0), float4-coalesced ----
    {
        int g = blockIdx.x * BLOCK + tid;
        if (g < LUTN / 4) {                  // 26952 float4s
            *(float4*)(out + g * 4) = *(const float4*)(lut + g * 4);
        } else if (g == LUTN / 4) {          // 3-float tail (LUTN odd)
            out[LUTN - 3] = lut[LUTN - 3];
            out[LUTN - 2] = lut[LUTN - 2];
            out[LUTN - 1] = lut[LUTN - 1];
        }
    }

    // ---- Phase B: pack lut -> LDS (8:8:8, byte3=0), lane-coalesced ----
    // quant err <= 0.5/255 = 2e-3 << 2e-2 threshold.
    for (int k = tid; k < TABN; k += BLOCK) {
        float r = lut[k], g = lut[S3 + k], b = lut[2 * S3 + k];
        unsigned qr = (unsigned)fmaf(r, 255.f, 0.5f);
        unsigned qg = (unsigned)fmaf(g, 255.f, 0.5f);
        unsigned qb = (unsigned)fmaf(b, 255.f, 0.5f);
        tab[k] = qr | (qg << 8) | (qb << 16);
    }
    __syncthreads();

    // ---- Phase C: 2 tiles x 8 px, full static unroll ----
    const float inv = 1.0f / 255.0f;
#pragma unroll
    for (int t = 0; t < 2; ++t) {
        int pa = base_px + (tid + (2 * t) * BLOCK) * 4;
        int pb = base_px + (tid + (2 * t + 1) * BLOCK) * 4;
        float4 xa = *(const float4*)(img + pa);
        float4 xb = *(const float4*)(img + pb);
        float4 ya = *(const float4*)(img + NPIX + pa);
        float4 yb = *(const float4*)(img + NPIX + pb);
        float4 za = *(const float4*)(img + 2 * NPIX + pa);
        float4 zb = *(const float4*)(img + 2 * NPIX + pb);
        float ax[8] = {xa.x, xa.y, xa.z, xa.w, xb.x, xb.y, xb.z, xb.w};
        float ay[8] = {ya.x, ya.y, ya.z, ya.w, yb.x, yb.y, yb.z, yb.w};
        float az[8] = {za.x, za.y, za.z, za.w, zb.x, zb.y, zb.z, zb.w};
        float rr[8], gg[8], bb[8];
#pragma unroll
        for (int i = 0; i < 8; ++i) {
            float px = ax[i] * 32.0f;          // img in [0,1) -> px in [0,32)
            float py = ay[i] * 32.0f;
            float pz = az[i] * 32.0f;
            int ix = (int)px & 31;             // &31: free OOB guard
            int iy = (int)py & 31;
            int iz = (int)pz & 31;
            float fx = __builtin_amdgcn_fractf(px);
            float fy = __builtin_amdgcn_fractf(py);
            float fz = __builtin_amdgcn_fractf(pz);
            int base = (iz * S + iy) * S + ix;

            unsigned c000 = tab[base],           c001 = tab[base + 1];
            unsigned c010 = tab[base + S],       c011 = tab[base + S + 1];
            unsigned c100 = tab[base + S2],      c101 = tab[base + S2 + 1];
            unsigned c110 = tab[base + S2 + S],  c111 = tab[base + S2 + S + 1];

            // weights-form trilerp: one weight set, 8 FMAs per channel
            float gx = 1.f - fx, gy = 1.f - fy, gz = 1.f - fz;
            float a00 = gy * gz, a10 = fy * gz, a01 = gy * fz, a11 = fy * fz;
            float w0 = gx * a00, w1 = fx * a00, w2 = gx * a10, w3 = fx * a10;
            float w4 = gx * a01, w5 = fx * a01, w6 = gx * a11, w7 = fx * a11;

            float R = 0.f, G = 0.f, B = 0.f;
            // byte extracts -> v_cvt_f32_ubyte{0,1,2}
#define ACC(c, w)                                                         \
            R = fmaf((float)((c) & 0xffu), (w), R);                       \
            G = fmaf((float)(((c) >> 8) & 0xffu), (w), G);                \
            B = fmaf((float)(((c) >> 16) & 0xffu), (w), B);
            ACC(c000, w0) ACC(c001, w1) ACC(c010, w2) ACC(c011, w3)
            ACC(c100, w4) ACC(c101, w5) ACC(c110, w6) ACC(c111, w7)
#undef ACC
            rr[i] = R * inv; gg[i] = G * inv; bb[i] = B * inv;
        }
        // stores: result region starts at odd float offset; (p+1) even ->
        // scalar, float2, scalar per 4-px group
#pragma unroll
        for (int g4 = 0; g4 < 2; ++g4) {
            int p = g4 ? pb : pa;
            const float* vr = rr + g4 * 4;
            const float* vg = gg + g4 * 4;
            const float* vb = bb + g4 * 4;
#pragma unroll
            for (int ch = 0; ch < 3; ++ch) {
                float* o = res + (size_t)ch * NPIX + p;
                const float* v = ch == 0 ? vr : (ch == 1 ? vg : vb);
                o[0] = v[0];
                *(float2*)(o + 1) = make_float2(v[1], v[2]);
                o[3] = v[3];
            }
        }
    }
}

extern "C" void kernel_launch(void* const* d_in, const int* in_sizes, int n_in,
                              void* d_out, int out_size, void* d_ws, size_t ws_size,
                              hipStream_t stream) {
    const float* lut = (const float*)d_in[0];
    const float* img = (const float*)d_in[1];
    float* out = (float*)d_out;

    // Allow >64KB dynamic LDS (idempotent attribute set, capture-safe).
    (void)hipFuncSetAttribute((const void*)trilerp_fused,
                              hipFuncAttributeMaxDynamicSharedMemorySize, TABB);

    trilerp_fused<<<GRID, BLOCK, TABB, stream>>>(img, lut, out);
}